// Round 2
// baseline (177.341 us; speedup 1.0000x reference)
//
#include <hip/hip_runtime.h>

#define BATCH 32
#define SEQL 4096
#define NCH 128
#define CHUNK 128
#define WARMUP 256
#define EM 0.9f
#define OneEM 0.1f

__global__ __launch_bounds__(128) void mpe_kernel(
    const float* __restrict__ ts,
    const int* __restrict__ labels,
    const float* __restrict__ amounts,
    float* __restrict__ out)
{
    const int c = threadIdx.x;            // channel 0..127
    const int chunk = blockIdx.x;         // 0..SEQL/CHUNK-1
    const int b = blockIdx.y;

    const int s = chunk * CHUNK;                      // first output index
    const int w = (s >= WARMUP) ? (s - WARMUP) : 0;   // first staged index
    const int total = s + CHUNK - w;                  // staged element count

    __shared__ int   s_lab[WARMUP + CHUNK];
    __shared__ float s_amt[WARMUP + CHUNK];
    __shared__ float s_dlt[WARMUP + CHUNK];

    const size_t rowbase = (size_t)b * SEQL;

    // Stage inputs (coalesced), computing clipped time deltas on the fly.
    for (int i = c; i < total; i += 128) {
        int gl = w + i;
        s_lab[i] = labels[rowbase + gl];
        s_amt[i] = amounts[rowbase + gl];
        float d = 0.f;
        if (gl > 0) d = fminf(ts[rowbase + gl] - ts[rowbase + gl - 1], 100.f);
        s_dlt[i] = d;
    }
    __syncthreads();

    float p = 0.f, a = 0.f, dema = 0.f;
    int i = 0;

    if (w == 0) {
        // Exact init at gl=0: e[0] = x[0]
        int lab0 = s_lab[0];
        bool mine = (c == lab0);
        p = mine ? 1.f : 0.f;
        a = mine ? s_amt[0] : 0.f;
        dema = s_dlt[0];  // == 0
        if (s == 0) {
            // write step 0 (probs sum ≡ 1: EMA preserves one-hot row sum,
            // so skip the normalization divide; drift O(1e-6) ≪ thr 0.15)
            size_t base0 = rowbase * (size_t)(1 + 2 * NCH);
            out[base0 + 1 + c] = p;
            out[base0 + 1 + NCH + c] = __fdividef(a, fmaxf(p, 1e-6f));
            if (c == 0) out[base0] = dema;
        }
        i = 1;
    }

    const int out_begin = s - w;           // local index of first output step
    const int out_end = out_begin + CHUNK;

    // Warmup: evolve state only (redundant prefix, error <= 0.9^WARMUP ~ 2e-12)
    for (; i < out_begin; ++i) {
        int lab = s_lab[i];
        float ap = (c == lab) ? OneEM : 0.f;
        float aa = (c == lab) ? OneEM * s_amt[i] : 0.f;
        p = fmaf(p, EM, ap);
        a = fmaf(a, EM, aa);
        dema = fmaf(dema, EM, OneEM * s_dlt[i]);
    }

    // Output phase: evolve + write 257 floats per step.
    // Pointer-increment addressing: one += per step instead of a 64-bit mul.
    const int gl0 = w + ((i > out_begin) ? i : out_begin);
    float* po = out + (rowbase + gl0) * (size_t)(1 + 2 * NCH);
    for (; i < out_end; ++i) {
        int lab = s_lab[i];
        float ap = (c == lab) ? OneEM : 0.f;
        float aa = (c == lab) ? OneEM * s_amt[i] : 0.f;
        p = fmaf(p, EM, ap);
        a = fmaf(a, EM, aa);
        dema = fmaf(dema, EM, OneEM * s_dlt[i]);
        po[1 + c] = p;
        po[1 + NCH + c] = __fdividef(a, fmaxf(p, 1e-6f));
        if (c == 0) po[0] = dema;
        po += 1 + 2 * NCH;
    }
}

extern "C" void kernel_launch(void* const* d_in, const int* in_sizes, int n_in,
                              void* d_out, int out_size, void* d_ws, size_t ws_size,
                              hipStream_t stream) {
    const float* ts      = (const float*)d_in[0];
    const int*   labels  = (const int*)d_in[1];
    const float* amounts = (const float*)d_in[2];
    float* out = (float*)d_out;

    dim3 grid(SEQL / CHUNK, BATCH);
    mpe_kernel<<<grid, 128, 0, stream>>>(ts, labels, amounts, out);
}

// Round 3
// 159.486 us; speedup vs baseline: 1.1120x; 1.1120x over previous
//
#include <hip/hip_runtime.h>

#define BATCH 32
#define SEQL 4096
#define NCH 128
#define CHUNK 64
#define WARMUP 192
#define STAGE (WARMUP + CHUNK)   // 256 staged steps max
#define EM 0.9f
#define OneEM 0.1f

// One block = one (batch, 64-step output chunk). 128 threads = 1 channel each.
// EMA memory is geometric: 0.9^192 ~ 1.6e-9; worst-case amplification through
// the 1e-6 clip is 1e6 => chunk-truncation error <= ~1.6e-3 (threshold 0.15).
// probs normalizer is identically 1 (EMA preserves one-hot row sums) => skip it.
__global__ __launch_bounds__(128) void mpe_kernel(
    const float* __restrict__ ts,
    const int* __restrict__ labels,
    const float* __restrict__ amounts,
    float* __restrict__ out)
{
    const int c = threadIdx.x;            // channel 0..127
    const int chunk = blockIdx.x;         // 0..63
    const int b = blockIdx.y;

    const int s = chunk * CHUNK;                      // first output index
    const int w = (s >= WARMUP) ? (s - WARMUP) : 0;   // first staged index
    const int total = s + CHUNK - w;                  // staged element count

    // packed per-step record: {0.1*amt, 0.1*clipped_dt, label bits, pad}
    __shared__ float4 st[STAGE];

    const size_t rowbase = (size_t)b * SEQL;
    const float* tsr = ts + rowbase;

    for (int i = c; i < total; i += 128) {
        int gl = w + i;
        float amt01 = OneEM * amounts[rowbase + gl];
        float d01 = 0.f;
        if (gl > 0) d01 = OneEM * fminf(tsr[gl] - tsr[gl - 1], 100.f);
        st[i] = make_float4(amt01, d01, __int_as_float(labels[rowbase + gl]), 0.f);
    }
    __syncthreads();

    float p = 0.f, a = 0.f, dema = 0.f;
    int i = 0;
    const int out_begin = s - w;           // local index of first output step
    const int out_end = out_begin + CHUNK;

    if (w == 0) {
        // Exact init at gl=0: carry = x[0]
        float4 v = st[0];
        bool mine = (c == __float_as_int(v.z));
        p = mine ? 1.f : 0.f;
        a = mine ? v.x * 10.f : 0.f;   // st holds 0.1*amt; undo (1-ulp rounding)
        dema = 0.f;                    // first delta is 0 by construction
        if (s == 0) {
            size_t base0 = rowbase * (size_t)(1 + 2 * NCH);
            out[base0 + 1 + c] = p;
            out[base0 + 1 + NCH + c] = __fdividef(a, fmaxf(p, 1e-6f));
            if (c == 0) out[base0] = dema;
        }
        i = 1;
    }

    // Warmup: evolve state only (redundant prefix). cndmask + 3 fmac per step.
    #pragma unroll 4
    for (; i < out_begin; ++i) {
        float4 v = st[i];
        bool mine = (c == __float_as_int(v.z));
        p = fmaf(p, EM, mine ? OneEM : 0.f);
        a = fmaf(a, EM, mine ? v.x : 0.f);
        dema = fmaf(dema, EM, v.y);
    }

    // Output phase: evolve + write 257 floats/step; pointer-increment addressing.
    float* po = out + (rowbase + w + i) * (size_t)(1 + 2 * NCH);
    #pragma unroll 2
    for (; i < out_end; ++i) {
        float4 v = st[i];
        bool mine = (c == __float_as_int(v.z));
        p = fmaf(p, EM, mine ? OneEM : 0.f);
        a = fmaf(a, EM, mine ? v.x : 0.f);
        dema = fmaf(dema, EM, v.y);
        po[1 + c] = p;
        po[1 + NCH + c] = __fdividef(a, fmaxf(p, 1e-6f));
        if (c == 0) po[0] = dema;
        po += 1 + 2 * NCH;
    }
}

extern "C" void kernel_launch(void* const* d_in, const int* in_sizes, int n_in,
                              void* d_out, int out_size, void* d_ws, size_t ws_size,
                              hipStream_t stream) {
    const float* ts      = (const float*)d_in[0];
    const int*   labels  = (const int*)d_in[1];
    const float* amounts = (const float*)d_in[2];
    float* out = (float*)d_out;

    dim3 grid(SEQL / CHUNK, BATCH);   // 64 x 32 = 2048 blocks
    mpe_kernel<<<grid, 128, 0, stream>>>(ts, labels, amounts, out);
}